// Round 1
// baseline (227.533 us; speedup 1.0000x reference)
//
#include <hip/hip_runtime.h>
#include <math.h>

#define NIMG 32
#define CDIM 256
#define KCL  64
#define SPIX 4096

// ---------------- K0: transpose conv_w (K x C) -> wT (C x K) ----------------
__global__ __launch_bounds__(256) void k_wt(const float* __restrict__ w, float* __restrict__ wT) {
    int g = blockIdx.x * 256 + threadIdx.x;   // g = k*CDIM + c
    if (g < KCL * CDIM) {
        int k = g / CDIM, c = g % CDIM;
        wT[c * KCL + k] = w[g];
    }
}

// ---------------- K1: per-pixel norm + logits + softmax -> aT, inv_norm -----
// grid 512 = (n, 16 chunks of 256 px), 256 threads, thread = pixel
__global__ __launch_bounds__(256) void k_logits(const float* __restrict__ x,
                                                const float* __restrict__ wT,
                                                const float* __restrict__ b,
                                                float* __restrict__ aT,
                                                float* __restrict__ inv_norm) {
    int blk = blockIdx.x;
    int n = blk >> 4, ch = blk & 15;
    int s = ch * 256 + threadIdx.x;
    const float* xp = x + ((size_t)n * CDIM) * SPIX + s;

    float acc[KCL];
    #pragma unroll
    for (int k = 0; k < KCL; k++) acc[k] = 0.f;
    float nrm = 0.f;

    for (int c = 0; c < CDIM; c++) {
        float xv = xp[(size_t)c * SPIX];          // coalesced across lanes
        nrm = fmaf(xv, xv, nrm);
        const float4* w4 = (const float4*)(wT + c * KCL);  // block-uniform address
        #pragma unroll
        for (int j = 0; j < 16; j++) {
            float4 wv = w4[j];
            acc[4*j+0] = fmaf(wv.x, xv, acc[4*j+0]);
            acc[4*j+1] = fmaf(wv.y, xv, acc[4*j+1]);
            acc[4*j+2] = fmaf(wv.z, xv, acc[4*j+2]);
            acc[4*j+3] = fmaf(wv.w, xv, acc[4*j+3]);
        }
    }

    float invn = 1.0f / fmaxf(sqrtf(nrm), 1e-12f);
    inv_norm[n * SPIX + s] = invn;

    float m = -1e30f;
    #pragma unroll
    for (int k = 0; k < KCL; k++) { acc[k] = fmaf(acc[k], invn, b[k]); m = fmaxf(m, acc[k]); }
    float sum = 0.f;
    #pragma unroll
    for (int k = 0; k < KCL; k++) { float e = __expf(acc[k] - m); acc[k] = e; sum += e; }
    float r = 1.0f / sum;

    float4* ap = (float4*)(aT + ((size_t)(n * SPIX + s)) * KCL);
    #pragma unroll
    for (int j = 0; j < 16; j++) {
        float4 v;
        v.x = acc[4*j+0] * r; v.y = acc[4*j+1] * r;
        v.z = acc[4*j+2] * r; v.w = acc[4*j+3] * r;
        ap[j] = v;
    }
}

// ---------------- K2: asum partials: asum_part[n][ch][k] = sum_s a ----------
// grid 512 = (n, 16 chunks of 256 px), 256 threads (k = tid%64, g = tid/64)
__global__ __launch_bounds__(256) void k_asum(const float* __restrict__ aT,
                                              float* __restrict__ asum_part) {
    int blk = blockIdx.x;
    int n = blk >> 4, ch = blk & 15;
    int tid = threadIdx.x;
    int k = tid & 63, g = tid >> 6;
    const float* ap = aT + ((size_t)(n * SPIX + ch * 256)) * KCL;
    float acc = 0.f;
    for (int i = 0; i < 64; i++) acc += ap[(size_t)(g * 64 + i) * KCL + k];  // coalesced
    __shared__ float red[256];
    red[tid] = acc;
    __syncthreads();
    if (tid < 64) asum_part[blk * KCL + tid] = red[tid] + red[64+tid] + red[128+tid] + red[192+tid];
}

// ---------------- K3: vlad partials: vlad_part[blk][k][c] -------------------
// grid 512 = (n, 16 chunks of 256 px), 256 threads; thread owns channel c=tid
__global__ __launch_bounds__(256) void k_vlad(const float* __restrict__ x,
                                              const float* __restrict__ inv_norm,
                                              const float* __restrict__ aT,
                                              float* __restrict__ vlad_part) {
    int blk = blockIdx.x;
    int n = blk >> 4, ch = blk & 15;
    int s0 = ch * 256;
    __shared__ float xt[64 * 257];  // [pixel][channel], padded: conflict-free
    int tid = threadIdx.x;
    int p = tid & 63, cq = tid >> 6;

    float acc[KCL];
    #pragma unroll
    for (int k = 0; k < KCL; k++) acc[k] = 0.f;

    for (int t = 0; t < 4; t++) {
        int sb = s0 + t * 64;
        float invp = inv_norm[n * SPIX + sb + p];
        __syncthreads();
        for (int i = 0; i < 64; i++) {
            int c = cq * 64 + i;
            float xv = x[((size_t)n * CDIM + c) * SPIX + sb + p];  // coalesced
            xt[p * 257 + c] = xv * invp;
        }
        __syncthreads();
        const float4* ap0 = (const float4*)(aT + ((size_t)(n * SPIX + sb)) * KCL);
        for (int pp = 0; pp < 64; pp++) {
            float xn = xt[pp * 257 + tid];         // conflict-free
            const float4* ap = ap0 + pp * 16;      // block-uniform address
            #pragma unroll
            for (int q = 0; q < 16; q++) {
                float4 a4 = ap[q];
                acc[4*q+0] = fmaf(a4.x, xn, acc[4*q+0]);
                acc[4*q+1] = fmaf(a4.y, xn, acc[4*q+1]);
                acc[4*q+2] = fmaf(a4.z, xn, acc[4*q+2]);
                acc[4*q+3] = fmaf(a4.w, xn, acc[4*q+3]);
            }
        }
    }
    float* vp = vlad_part + (size_t)blk * KCL * CDIM;
    #pragma unroll
    for (int k = 0; k < KCL; k++) vp[k * CDIM + tid] = acc[k];
}

// ---------------- K4: combine partials + centroid subtract + intra-norm ----
// grid 2048 = (n,k), 256 threads (c = tid)
__global__ __launch_bounds__(256) void k_combine(const float* __restrict__ vlad_part,
                                                 const float* __restrict__ asum_part,
                                                 const float* __restrict__ cent,
                                                 float* __restrict__ out,
                                                 float* __restrict__ rs) {
    int blk = blockIdx.x;          // n*64 + k
    int n = blk >> 6, k = blk & 63;
    int c = threadIdx.x;
    float v = 0.f;
    for (int j = 0; j < 16; j++)
        v += vlad_part[(((size_t)(n * 16 + j)) * KCL + k) * CDIM + c];
    float as = 0.f;
    for (int j = 0; j < 16; j++)
        as += asum_part[(n * 16 + j) * KCL + k];
    v = fmaf(-as, cent[k * CDIM + c], v);

    float t = v * v;
    #pragma unroll
    for (int off = 32; off > 0; off >>= 1) t += __shfl_xor(t, off, 64);
    __shared__ float w4[4];
    int lane = threadIdx.x & 63, wid = threadIdx.x >> 6;
    if (lane == 0) w4[wid] = t;
    __syncthreads();
    float ss = w4[0] + w4[1] + w4[2] + w4[3];
    float inv = 1.0f / fmaxf(sqrtf(ss), 1e-12f);
    out[(size_t)blk * CDIM + c] = v * inv;
    if (threadIdx.x == 0) rs[blk] = ss * inv * inv;
}

// ---------------- K5: global L2 normalize per image (in place) --------------
// grid 256 = (n, 8), 256 threads
__global__ __launch_bounds__(256) void k_gnorm(const float* __restrict__ rs,
                                               float* __restrict__ out) {
    int n = blockIdx.x >> 3, j = blockIdx.x & 7;
    float ss = 0.f;
    for (int k = 0; k < KCL; k++) ss += rs[n * KCL + k];
    float g = 1.0f / fmaxf(sqrtf(ss), 1e-12f);
    size_t base = (size_t)n * (KCL * CDIM) + j * 2048 + threadIdx.x;
    for (int i = 0; i < 8; i++) out[base + i * 256] *= g;
}

extern "C" void kernel_launch(void* const* d_in, const int* in_sizes, int n_in,
                              void* d_out, int out_size, void* d_ws, size_t ws_size,
                              hipStream_t stream) {
    const float* x    = (const float*)d_in[0];   // [32][256][64][64]
    const float* w    = (const float*)d_in[1];   // [64][256]
    const float* b    = (const float*)d_in[2];   // [64]
    const float* cent = (const float*)d_in[3];   // [64][256]
    float* out = (float*)d_out;

    float* ws = (float*)d_ws;
    float* wT        = ws;                        // 16384
    float* inv_norm  = wT + 16384;                // 131072
    float* aT        = inv_norm + 131072;         // 32*4096*64 = 8388608
    float* vlad_part = aT + 8388608;              // 512*64*256 = 8388608
    float* asum_part = vlad_part + 8388608;       // 512*64 = 32768
    float* rs        = asum_part + 32768;         // 2048

    k_wt<<<64, 256, 0, stream>>>(w, wT);
    k_logits<<<512, 256, 0, stream>>>(x, wT, b, aT, inv_norm);
    k_asum<<<512, 256, 0, stream>>>(aT, asum_part);
    k_vlad<<<512, 256, 0, stream>>>(x, inv_norm, aT, vlad_part);
    k_combine<<<2048, 256, 0, stream>>>(vlad_part, asum_part, cent, out, rs);
    k_gnorm<<<256, 256, 0, stream>>>(rs, out);
}

// Round 2
// 227.254 us; speedup vs baseline: 1.0012x; 1.0012x over previous
//
#include <hip/hip_runtime.h>
#include <math.h>

#define NIMG 32
#define CDIM 256
#define KCL  64
#define SPIX 4096

// ---------------- K0: transpose conv_w (K x C) -> wT (C x K) ----------------
__global__ __launch_bounds__(256) void k_wt(const float* __restrict__ w, float* __restrict__ wT) {
    int g = blockIdx.x * 256 + threadIdx.x;   // g = k*CDIM + c
    if (g < KCL * CDIM) {
        int k = g / CDIM, c = g % CDIM;
        wT[c * KCL + k] = w[g];
    }
}

// ---------------- K1: per-pixel norm + logits + softmax -> aT, inv_norm -----
// grid 512 = (n, 16 chunks of 256 px), 256 threads, thread = pixel
// __launch_bounds__(256, 4): 128-VGPR budget so acc[64] stays in registers
// (round 1: default budget -> 52 VGPRs -> acc spilled to scratch -> 170 us).
__global__ __launch_bounds__(256, 4) void k_logits(const float* __restrict__ x,
                                                   const float* __restrict__ wT,
                                                   const float* __restrict__ b,
                                                   float* __restrict__ aT,
                                                   float* __restrict__ inv_norm) {
    int blk = blockIdx.x;
    int n = blk >> 4, ch = blk & 15;
    int s = ch * 256 + threadIdx.x;
    const float* xp = x + ((size_t)n * CDIM) * SPIX + s;

    float acc[KCL];
    #pragma unroll
    for (int k = 0; k < KCL; k++) acc[k] = 0.f;
    float nrm = 0.f;

    for (int c = 0; c < CDIM; c++) {
        float xv = xp[(size_t)c * SPIX];          // coalesced across lanes
        nrm = fmaf(xv, xv, nrm);
        const float4* w4 = (const float4*)(wT + c * KCL);  // block-uniform address
        #pragma unroll
        for (int j = 0; j < 16; j++) {
            float4 wv = w4[j];
            acc[4*j+0] = fmaf(wv.x, xv, acc[4*j+0]);
            acc[4*j+1] = fmaf(wv.y, xv, acc[4*j+1]);
            acc[4*j+2] = fmaf(wv.z, xv, acc[4*j+2]);
            acc[4*j+3] = fmaf(wv.w, xv, acc[4*j+3]);
        }
    }

    float invn = 1.0f / fmaxf(sqrtf(nrm), 1e-12f);
    inv_norm[n * SPIX + s] = invn;

    float m = -1e30f;
    #pragma unroll
    for (int k = 0; k < KCL; k++) { acc[k] = fmaf(acc[k], invn, b[k]); m = fmaxf(m, acc[k]); }
    float sum = 0.f;
    #pragma unroll
    for (int k = 0; k < KCL; k++) { float e = __expf(acc[k] - m); acc[k] = e; sum += e; }
    float r = 1.0f / sum;

    float4* ap = (float4*)(aT + ((size_t)(n * SPIX + s)) * KCL);
    #pragma unroll
    for (int j = 0; j < 16; j++) {
        float4 v;
        v.x = acc[4*j+0] * r; v.y = acc[4*j+1] * r;
        v.z = acc[4*j+2] * r; v.w = acc[4*j+3] * r;
        ap[j] = v;
    }
}

// ---------------- K2: asum partials: asum_part[n][ch][k] = sum_s a ----------
// grid 512 = (n, 16 chunks of 256 px), 256 threads (k = tid%64, g = tid/64)
__global__ __launch_bounds__(256) void k_asum(const float* __restrict__ aT,
                                              float* __restrict__ asum_part) {
    int blk = blockIdx.x;
    int n = blk >> 4, ch = blk & 15;
    int tid = threadIdx.x;
    int k = tid & 63, g = tid >> 6;
    const float* ap = aT + ((size_t)(n * SPIX + ch * 256)) * KCL;
    float acc = 0.f;
    for (int i = 0; i < 64; i++) acc += ap[(size_t)(g * 64 + i) * KCL + k];  // coalesced
    __shared__ float red[256];
    red[tid] = acc;
    __syncthreads();
    if (tid < 64) asum_part[blk * KCL + tid] = red[tid] + red[64+tid] + red[128+tid] + red[192+tid];
}

// ---------------- K3: vlad partials: vlad_part[blk][k][c] -------------------
// grid 512 = (n, 16 chunks of 256 px), 256 threads; thread owns channel c=tid
// Same 128-VGPR budget fix as k_logits (acc[64] per thread).
__global__ __launch_bounds__(256, 4) void k_vlad(const float* __restrict__ x,
                                                 const float* __restrict__ inv_norm,
                                                 const float* __restrict__ aT,
                                                 float* __restrict__ vlad_part) {
    int blk = blockIdx.x;
    int n = blk >> 4, ch = blk & 15;
    int s0 = ch * 256;
    __shared__ float xt[64 * 257];  // [pixel][channel], padded: conflict-free
    int tid = threadIdx.x;
    int p = tid & 63, cq = tid >> 6;

    float acc[KCL];
    #pragma unroll
    for (int k = 0; k < KCL; k++) acc[k] = 0.f;

    for (int t = 0; t < 4; t++) {
        int sb = s0 + t * 64;
        float invp = inv_norm[n * SPIX + sb + p];
        __syncthreads();
        for (int i = 0; i < 64; i++) {
            int c = cq * 64 + i;
            float xv = x[((size_t)n * CDIM + c) * SPIX + sb + p];  // coalesced
            xt[p * 257 + c] = xv * invp;
        }
        __syncthreads();
        const float4* ap0 = (const float4*)(aT + ((size_t)(n * SPIX + sb)) * KCL);
        for (int pp = 0; pp < 64; pp++) {
            float xn = xt[pp * 257 + tid];         // conflict-free
            const float4* ap = ap0 + pp * 16;      // block-uniform address
            #pragma unroll
            for (int q = 0; q < 16; q++) {
                float4 a4 = ap[q];
                acc[4*q+0] = fmaf(a4.x, xn, acc[4*q+0]);
                acc[4*q+1] = fmaf(a4.y, xn, acc[4*q+1]);
                acc[4*q+2] = fmaf(a4.z, xn, acc[4*q+2]);
                acc[4*q+3] = fmaf(a4.w, xn, acc[4*q+3]);
            }
        }
    }
    float* vp = vlad_part + (size_t)blk * KCL * CDIM;
    #pragma unroll
    for (int k = 0; k < KCL; k++) vp[k * CDIM + tid] = acc[k];
}

// ---------------- K4: combine partials + centroid subtract + intra-norm ----
// grid 2048 = (n,k), 256 threads (c = tid)
__global__ __launch_bounds__(256) void k_combine(const float* __restrict__ vlad_part,
                                                 const float* __restrict__ asum_part,
                                                 const float* __restrict__ cent,
                                                 float* __restrict__ out,
                                                 float* __restrict__ rs) {
    int blk = blockIdx.x;          // n*64 + k
    int n = blk >> 6, k = blk & 63;
    int c = threadIdx.x;
    float v = 0.f;
    for (int j = 0; j < 16; j++)
        v += vlad_part[(((size_t)(n * 16 + j)) * KCL + k) * CDIM + c];
    float as = 0.f;
    for (int j = 0; j < 16; j++)
        as += asum_part[(n * 16 + j) * KCL + k];
    v = fmaf(-as, cent[k * CDIM + c], v);

    float t = v * v;
    #pragma unroll
    for (int off = 32; off > 0; off >>= 1) t += __shfl_xor(t, off, 64);
    __shared__ float w4[4];
    int lane = threadIdx.x & 63, wid = threadIdx.x >> 6;
    if (lane == 0) w4[wid] = t;
    __syncthreads();
    float ss = w4[0] + w4[1] + w4[2] + w4[3];
    float inv = 1.0f / fmaxf(sqrtf(ss), 1e-12f);
    out[(size_t)blk * CDIM + c] = v * inv;
    if (threadIdx.x == 0) rs[blk] = ss * inv * inv;
}

// ---------------- K5: global L2 normalize per image (in place) --------------
// grid 256 = (n, 8), 256 threads
__global__ __launch_bounds__(256) void k_gnorm(const float* __restrict__ rs,
                                               float* __restrict__ out) {
    int n = blockIdx.x >> 3, j = blockIdx.x & 7;
    float ss = 0.f;
    for (int k = 0; k < KCL; k++) ss += rs[n * KCL + k];
    float g = 1.0f / fmaxf(sqrtf(ss), 1e-12f);
    size_t base = (size_t)n * (KCL * CDIM) + j * 2048 + threadIdx.x;
    for (int i = 0; i < 8; i++) out[base + i * 256] *= g;
}

extern "C" void kernel_launch(void* const* d_in, const int* in_sizes, int n_in,
                              void* d_out, int out_size, void* d_ws, size_t ws_size,
                              hipStream_t stream) {
    const float* x    = (const float*)d_in[0];   // [32][256][64][64]
    const float* w    = (const float*)d_in[1];   // [64][256]
    const float* b    = (const float*)d_in[2];   // [64]
    const float* cent = (const float*)d_in[3];   // [64][256]
    float* out = (float*)d_out;

    float* ws = (float*)d_ws;
    float* wT        = ws;                        // 16384
    float* inv_norm  = wT + 16384;                // 131072
    float* aT        = inv_norm + 131072;         // 32*4096*64 = 8388608
    float* vlad_part = aT + 8388608;              // 512*64*256 = 8388608
    float* asum_part = vlad_part + 8388608;       // 512*64 = 32768
    float* rs        = asum_part + 32768;         // 2048

    k_wt<<<64, 256, 0, stream>>>(w, wT);
    k_logits<<<512, 256, 0, stream>>>(x, wT, b, aT, inv_norm);
    k_asum<<<512, 256, 0, stream>>>(aT, asum_part);
    k_vlad<<<512, 256, 0, stream>>>(x, inv_norm, aT, vlad_part);
    k_combine<<<2048, 256, 0, stream>>>(vlad_part, asum_part, cent, out, rs);
    k_gnorm<<<256, 256, 0, stream>>>(rs, out);
}